// Round 5
// baseline (141.570 us; speedup 1.0000x reference)
//
#include <hip/hip_runtime.h>

// Problem constants
#define BATCH  4
#define SEQL   2048
#define DMODEL 1024
#define NST    16
#define CT     64            // chunk length T
#define NCH    (SEQL / CT)   // 32 chunks

// ws layout (float offsets)
#define WS_P     0           // P[sigma][m]   = (A^(T-1-sigma) B)[m]      : CT*16
#define WS_W     1024        // W[tau][m]     = (B^T A^(tau+1))[m]        : CT*16
#define WS_KV    2048        // kvext[128]: kvext[63+d] = B^T A^d B, 0 for d<0
#define WS_APOW  2176        // Apow[m][k]    = (A^CT)[m][k]              : 256
#define WS_HIN   4096        // hin[b][j][d][m] = s_{j-1}                 : B*NCH*D*16

// ---------------------------------------------------------------------------
// Setup: block delta (0..64) computes A^delta in fp64 via binary powering,
// then emits its slice of the tables.
// ---------------------------------------------------------------------------
__global__ __launch_bounds__(256) void setup_tables(const float* __restrict__ A,
                                                    const float* __restrict__ Bv,
                                                    float* __restrict__ ws) {
    __shared__ double buf0[256], buf1[256], buf2[256], buf3[256];
    __shared__ double bd[16], vtmp[16];
    double* S  = buf0;
    double* R  = buf1;
    double* Ta = buf2;
    double* Tb = buf3;
    const int t  = threadIdx.x;
    const int i  = t >> 4;
    const int kk = t & 15;
    const int delta = blockIdx.x;   // 0..64

    S[t] = (double)A[t];
    R[t] = (i == kk) ? 1.0 : 0.0;
    if (t < 16) bd[t] = (double)Bv[t];
    __syncthreads();

    for (int sb = 0; sb < 7; ++sb) {
        if ((delta >> sb) & 1) {
            double acc = 0.0;
            #pragma unroll
            for (int l = 0; l < 16; ++l) acc += R[i * 16 + l] * S[l * 16 + kk];
            Ta[t] = acc;
            __syncthreads();
            double* tmp = R; R = Ta; Ta = tmp;
        }
        if (sb < 6) {
            double acc = 0.0;
            #pragma unroll
            for (int l = 0; l < 16; ++l) acc += S[i * 16 + l] * S[l * 16 + kk];
            Tb[t] = acc;
            __syncthreads();
            double* tmp = S; S = Tb; Tb = tmp;
        }
    }
    // R now holds A^delta (fp64)

    if (delta < CT) {
        if (t < 16) {   // m = t : P[CT-1-delta][m] = (A^delta B)[m]
            double acc = 0.0;
            #pragma unroll
            for (int k = 0; k < 16; ++k) acc += R[t * 16 + k] * bd[k];
            ws[WS_P + (CT - 1 - delta) * 16 + t] = (float)acc;
            vtmp[t] = acc;
        }
        __syncthreads();
        if (t == 0) {   // k_delta = B^T A^delta B
            double kd = 0.0;
            for (int m = 0; m < 16; ++m) kd += bd[m] * vtmp[m];
            ws[WS_KV + 63 + delta] = (float)kd;
        }
    }
    if (delta >= 1 && t < 16) {   // W[delta-1][m] = sum_n B[n] (A^delta)[n][m]
        double acc = 0.0;
        #pragma unroll
        for (int n = 0; n < 16; ++n) acc += bd[n] * R[n * 16 + t];
        ws[WS_W + (delta - 1) * 16 + t] = (float)acc;
    }
    if (delta == CT) ws[WS_APOW + t] = (float)R[t];   // A^CT carry matrix
    if (delta == 0 && t < 63) ws[WS_KV + t] = 0.0f;   // zero-pad negative lags
}

// ---------------------------------------------------------------------------
// K1: chunk state via LDS staging. Block (b,j), 512 threads, reads its whole
// 256-KB x chunk as CONTIGUOUS float4 runs (DRAM-linear), in 8 double-
// buffered 32-KB stages. Thread computes 2 channels (t, t+512) from LDS.
// c_j[m] = sum_sigma P[sigma][m] x[sigma]
// ---------------------------------------------------------------------------
__global__ __launch_bounds__(512) void k1_chunkstate(const float* __restrict__ x,
                                                     const float* __restrict__ ws,
                                                     float* __restrict__ cbuf) {
    __shared__ __align__(16) float xs[2][8 * DMODEL];   // 2 x 32 KB = 64 KB
    const int blk = blockIdx.x;           // 128 = b*32 + j
    const int b   = blk >> 5;
    const int j   = blk & 31;
    const int t   = threadIdx.x;          // 0..511

    const float* __restrict__ xchunk = x + ((size_t)(b * SEQL + j * CT)) * DMODEL;
    const float* __restrict__ P = ws + WS_P;   // wave-uniform -> scalar cache

    float c0[16], c1[16];
    #pragma unroll
    for (int m = 0; m < 16; ++m) { c0[m] = 0.0f; c1[m] = 0.0f; }

    // preamble: stage rows 0..7 (32 KB contiguous)
    {
        const float4* src = (const float4*)xchunk;
        float4 pre[4];
        #pragma unroll
        for (int k = 0; k < 4; ++k) pre[k] = src[t + k * 512];
        #pragma unroll
        for (int k = 0; k < 4; ++k) ((float4*)xs[0])[t + k * 512] = pre[k];
    }
    __syncthreads();

    #pragma unroll
    for (int st = 0; st < 8; ++st) {
        float4 nxt[4];
        if (st < 7) {                     // prefetch next 8 rows (contiguous)
            const float4* src = (const float4*)(xchunk + (size_t)(st + 1) * 8 * DMODEL);
            #pragma unroll
            for (int k = 0; k < 4; ++k) nxt[k] = src[t + k * 512];
        }
        const float* xsb = xs[st & 1];
        #pragma unroll
        for (int s8 = 0; s8 < 8; ++s8) {  // compute while nxt loads in flight
            const int ss = st * 8 + s8;
            const float xv0 = xsb[s8 * DMODEL + t];
            const float xv1 = xsb[s8 * DMODEL + t + 512];
            #pragma unroll
            for (int m = 0; m < 16; ++m) {
                c0[m] = fmaf(P[ss * 16 + m], xv0, c0[m]);
                c1[m] = fmaf(P[ss * 16 + m], xv1, c1[m]);
            }
        }
        if (st < 7) {
            #pragma unroll
            for (int k = 0; k < 4; ++k) ((float4*)xs[(st + 1) & 1])[t + k * 512] = nxt[k];
        }
        __syncthreads();
    }

    // store c for both channels (wave-contiguous float4 runs)
    float4* out0 = (float4*)(cbuf + (((size_t)(b * NCH + j) * DMODEL) + t) * 16);
    float4* out1 = (float4*)(cbuf + (((size_t)(b * NCH + j) * DMODEL) + t + 512) * 16);
    #pragma unroll
    for (int q = 0; q < 4; ++q) {
        out0[q] = make_float4(c0[4 * q], c0[4 * q + 1], c0[4 * q + 2], c0[4 * q + 3]);
        out1[q] = make_float4(c1[4 * q], c1[4 * q + 1], c1[4 * q + 2], c1[4 * q + 3]);
    }
}

// ---------------------------------------------------------------------------
// K2: carry scan over chunks (UNCHANGED from R3). Thread = (channel d, m).
// All 32 chunk partials prefetched upfront, then serial shfl chain.
// s_j = Apow*s_{j-1} + c_j ; hin_j = s_{j-1}.
// ---------------------------------------------------------------------------
__global__ __launch_bounds__(256) void k2_carry(const float* __restrict__ cbuf,
                                                float* __restrict__ ws) {
    const int blk = blockIdx.x;           // 256 blocks
    const int b   = blk >> 6;
    const int d0  = (blk & 63) * 16;
    const int t   = threadIdx.x;
    const int m   = t & 15;
    const int ch  = t >> 4;
    const int d   = d0 + ch;
    const int laneBase = t & 48;          // 16-lane group base within wave

    const size_t base0   = (((size_t)(b * NCH) * DMODEL) + d) * 16 + m;
    const size_t jstride = (size_t)DMODEL * 16;

    float cpre[NCH];
    #pragma unroll
    for (int j = 0; j < NCH; ++j)
        cpre[j] = cbuf[base0 + (size_t)j * jstride];

    float Arow[16];
    #pragma unroll
    for (int k = 0; k < 16; ++k) Arow[k] = ws[WS_APOW + m * 16 + k];

    float* hin = ws + WS_HIN;
    float s = 0.0f;
    #pragma unroll
    for (int j = 0; j < NCH; ++j) {
        hin[base0 + (size_t)j * jstride] = s;
        float acc = cpre[j];
        #pragma unroll
        for (int k = 0; k < 16; ++k)
            acc = fmaf(Arow[k], __shfl(s, laneBase + k, 64), acc);
        s = acc;
    }
}

// ---------------------------------------------------------------------------
// K3: outputs via LDS staging. Block (b,j,quarter-D), 256 threads; stages
// x[64][256] in 8 double-buffered 8-KB stages (1-KB contiguous wave runs).
// y[64] accumulator in registers; kv/W tables in LDS (broadcast reads).
// y[tau] = W[tau].h_in + sum_{s<=tau} k[tau-s] x[s]
// Triangle grouped by 8 rows; kvext zero-padding covers tau<s inside a group.
// ---------------------------------------------------------------------------
__global__ __launch_bounds__(256) void k3_output(const float* __restrict__ x,
                                                 const float* __restrict__ ws,
                                                 float* __restrict__ y) {
    __shared__ __align__(16) float xs[2][8 * 256];      // 2 x 8 KB
    __shared__ float kvs[128];                          // 512 B
    __shared__ float Ws[CT * 16];                       // 4 KB
    const int blk = blockIdx.x;           // 512 = ((b*32 + j)*4 + q)
    const int b   = blk >> 7;
    const int j   = (blk >> 2) & 31;
    const int q   = blk & 3;
    const int t   = threadIdx.x;          // 0..255
    const int d   = q * 256 + t;

    const float* __restrict__ xchunk =
        x + ((size_t)(b * SEQL + j * CT)) * DMODEL + q * 256;  // row stride DMODEL

    // table copies (tiny, linear)
    if (t < 128) kvs[t] = ws[WS_KV + t];
    #pragma unroll
    for (int k = 0; k < 4; ++k) Ws[t + k * 256] = ws[WS_W + t + k * 256];

    // h_in: contiguous float4 per thread (4-KB wave runs)
    const float4* hinp = (const float4*)(ws + WS_HIN +
                         (((size_t)(b * NCH + j) * DMODEL) + d) * 16);
    float4 hv[4];
    #pragma unroll
    for (int k = 0; k < 4; ++k) hv[k] = hinp[k];

    // stage 0 prefetch: rows 0..7 of this quarter (1-KB contiguous wave runs)
    float4 pre[2];
    #pragma unroll
    for (int k = 0; k < 2; ++k) {
        const int f  = t + k * 256;       // float4 index in [0,512)
        const int sl = f >> 6;            // row 0..7
        const int c4 = f & 63;            // float4 col
        pre[k] = ((const float4*)(xchunk + (size_t)sl * DMODEL))[c4];
    }
    __syncthreads();                      // tables visible

    float h[16];
    #pragma unroll
    for (int k = 0; k < 4; ++k) {
        h[4 * k] = hv[k].x; h[4 * k + 1] = hv[k].y;
        h[4 * k + 2] = hv[k].z; h[4 * k + 3] = hv[k].w;
    }

    // correction: y[tau] = W[tau].h  (overlaps pre0 loads in flight)
    float yv[CT];
    #pragma unroll
    for (int tau = 0; tau < CT; ++tau) {
        float acc = 0.0f;
        #pragma unroll
        for (int m = 0; m < 16; ++m) acc = fmaf(Ws[tau * 16 + m], h[m], acc);
        yv[tau] = acc;
    }

    #pragma unroll
    for (int k = 0; k < 2; ++k) ((float4*)xs[0])[t + k * 256] = pre[k];
    __syncthreads();

    #pragma unroll
    for (int g = 0; g < 8; ++g) {
        float4 nxt[2];
        if (g < 7) {                      // prefetch rows (g+1)*8 .. +8
            #pragma unroll
            for (int k = 0; k < 2; ++k) {
                const int f  = t + k * 256;
                const int sl = f >> 6;
                const int c4 = f & 63;
                nxt[k] = ((const float4*)(xchunk +
                          (size_t)((g + 1) * 8 + sl) * DMODEL))[c4];
            }
        }
        const float* xsb = xs[g & 1];
        #pragma unroll
        for (int s8 = 0; s8 < 8; ++s8) {
            const int s = g * 8 + s8;
            const float xv = xsb[s8 * 256 + t];
            #pragma unroll
            for (int tau = g * 8; tau < CT; ++tau)   // tau<s hits kv zero-pad
                yv[tau] = fmaf(kvs[63 + tau - s], xv, yv[tau]);
        }
        if (g < 7) {
            #pragma unroll
            for (int k = 0; k < 2; ++k) ((float4*)xs[(g + 1) & 1])[t + k * 256] = nxt[k];
        }
        __syncthreads();
    }

    float* yp = y + ((size_t)(b * SEQL + j * CT)) * DMODEL + q * 256 + t;
    #pragma unroll
    for (int tau = 0; tau < CT; ++tau) yp[(size_t)tau * DMODEL] = yv[tau];
}

// ---------------------------------------------------------------------------
extern "C" void kernel_launch(void* const* d_in, const int* in_sizes, int n_in,
                              void* d_out, int out_size, void* d_ws, size_t ws_size,
                              hipStream_t stream) {
    (void)in_sizes; (void)n_in; (void)out_size; (void)ws_size;
    const float* x  = (const float*)d_in[0];
    const float* A  = (const float*)d_in[1];
    const float* Bv = (const float*)d_in[2];
    float* out = (float*)d_out;
    float* ws  = (float*)d_ws;

    // c scratch lives in d_out (dead before K3 overwrites it with y);
    // h_in + tables in ws.
    setup_tables<<<65, 256, 0, stream>>>(A, Bv, ws);
    k1_chunkstate<<<128, 512, 0, stream>>>(x, ws, out);
    k2_carry<<<256, 256, 0, stream>>>(out, ws);
    k3_output<<<512, 256, 0, stream>>>(x, ws, out);
}

// Round 6
// 129.042 us; speedup vs baseline: 1.0971x; 1.0971x over previous
//
#include <hip/hip_runtime.h>

// Problem constants
#define BATCH  4
#define SEQL   2048
#define DMODEL 1024
#define NST    16
#define CT     64            // chunk length T
#define NCH    (SEQL / CT)   // 32 chunks

// ws layout (float offsets)
#define WS_P     0           // P[sigma][m]   = (A^(T-1-sigma) B)[m]      : CT*16
#define WS_W     1024        // W[tau][m]     = (B^T A^(tau+1))[m]        : CT*16
#define WS_KV    2048        // kvext[128]: kvext[63+d] = B^T A^d B, 0 for d<0
#define WS_APOW  2176        // Apow[m][k]    = (A^CT)[m][k]              : 256
#define WS_HIN   4096        // hin[b][j][d][m] = s_{j-1}                 : B*NCH*D*16

// ---------------------------------------------------------------------------
// Setup: block delta (0..64) computes A^delta in fp64 via binary powering,
// then emits its slice of the tables.
// ---------------------------------------------------------------------------
__global__ __launch_bounds__(256) void setup_tables(const float* __restrict__ A,
                                                    const float* __restrict__ Bv,
                                                    float* __restrict__ ws) {
    __shared__ double buf0[256], buf1[256], buf2[256], buf3[256];
    __shared__ double bd[16], vtmp[16];
    double* S  = buf0;
    double* R  = buf1;
    double* Ta = buf2;
    double* Tb = buf3;
    const int t  = threadIdx.x;
    const int i  = t >> 4;
    const int kk = t & 15;
    const int delta = blockIdx.x;   // 0..64

    S[t] = (double)A[t];
    R[t] = (i == kk) ? 1.0 : 0.0;
    if (t < 16) bd[t] = (double)Bv[t];
    __syncthreads();

    for (int sb = 0; sb < 7; ++sb) {
        if ((delta >> sb) & 1) {
            double acc = 0.0;
            #pragma unroll
            for (int l = 0; l < 16; ++l) acc += R[i * 16 + l] * S[l * 16 + kk];
            Ta[t] = acc;
            __syncthreads();
            double* tmp = R; R = Ta; Ta = tmp;
        }
        if (sb < 6) {
            double acc = 0.0;
            #pragma unroll
            for (int l = 0; l < 16; ++l) acc += S[i * 16 + l] * S[l * 16 + kk];
            Tb[t] = acc;
            __syncthreads();
            double* tmp = S; S = Tb; Tb = tmp;
        }
    }
    // R now holds A^delta (fp64)

    if (delta < CT) {
        if (t < 16) {   // m = t : P[CT-1-delta][m] = (A^delta B)[m]
            double acc = 0.0;
            #pragma unroll
            for (int k = 0; k < 16; ++k) acc += R[t * 16 + k] * bd[k];
            ws[WS_P + (CT - 1 - delta) * 16 + t] = (float)acc;
            vtmp[t] = acc;
        }
        __syncthreads();
        if (t == 0) {   // k_delta = B^T A^delta B
            double kd = 0.0;
            for (int m = 0; m < 16; ++m) kd += bd[m] * vtmp[m];
            ws[WS_KV + 63 + delta] = (float)kd;
        }
    }
    if (delta >= 1 && t < 16) {   // W[delta-1][m] = sum_n B[n] (A^delta)[n][m]
        double acc = 0.0;
        #pragma unroll
        for (int n = 0; n < 16; ++n) acc += bd[n] * R[n * 16 + t];
        ws[WS_W + (delta - 1) * 16 + t] = (float)acc;
    }
    if (delta == CT) ws[WS_APOW + t] = (float)R[t];   // A^CT carry matrix
    if (delta == 0 && t < 63) ws[WS_KV + t] = 0.0f;   // zero-pad negative lags
}

// ---------------------------------------------------------------------------
// K1: chunk state. Block (b, j, quarter-D), 256 threads. One-shot LDS stage
// of x[64 sigma][256 d] (64 KB) via 16 independent float4 loads per thread
// (each load instr covers a 1-KB contiguous wave run; 16-deep MLP).
// Then c_j[m] = sum_sigma P[sigma][m] x[sigma][d] from LDS.
// 512 blocks, 2 blocks/CU (LDS-limited), VGPR ~70.
// ---------------------------------------------------------------------------
__global__ __launch_bounds__(256) void k1_chunkstate(const float* __restrict__ x,
                                                     const float* __restrict__ ws,
                                                     float* __restrict__ cbuf) {
    __shared__ __align__(16) float xs[CT * 256];        // 64 KB
    __shared__ float Ps[CT * 16];                       // 4 KB
    const int blk = blockIdx.x;           // 512 = ((b*32 + j)*4 + q)
    const int b   = blk >> 7;
    const int j   = (blk >> 2) & 31;
    const int q   = blk & 3;
    const int t   = threadIdx.x;          // 0..255

    const float* __restrict__ xq =
        x + ((size_t)(b * SEQL + j * CT)) * DMODEL + q * 256;   // row stride DMODEL

    // 16 independent float4 loads (1-KB wave runs, rows 4k..4k+3 per k)
    float4 st[16];
    #pragma unroll
    for (int k = 0; k < 16; ++k) {
        const int f   = k * 256 + t;      // float4 index in [0,4096)
        const int row = f >> 6;           // sigma row 0..63
        const int c4  = f & 63;           // float4 col within row
        st[k] = ((const float4*)(xq + (size_t)row * DMODEL))[c4];
    }
    #pragma unroll
    for (int k = 0; k < 4; ++k) Ps[t + k * 256] = ws[WS_P + t + k * 256];
    #pragma unroll
    for (int k = 0; k < 16; ++k) ((float4*)xs)[k * 256 + t] = st[k];
    __syncthreads();

    float c[16];
    #pragma unroll
    for (int m = 0; m < 16; ++m) c[m] = 0.0f;
    #pragma unroll
    for (int s = 0; s < CT; ++s) {
        const float xv = xs[s * 256 + t];           // 2-way bank alias: free
        #pragma unroll
        for (int m = 0; m < 16; ++m)
            c[m] = fmaf(Ps[s * 16 + m], xv, c[m]);  // broadcast
    }

    // contiguous 16-float c per thread -> 16-KB wave runs
    float4* outp = (float4*)(cbuf + (((size_t)(b * NCH + j) * DMODEL) + q * 256 + t) * 16);
    #pragma unroll
    for (int k = 0; k < 4; ++k)
        outp[k] = make_float4(c[4 * k], c[4 * k + 1], c[4 * k + 2], c[4 * k + 3]);
}

// ---------------------------------------------------------------------------
// K2: carry scan over chunks (unchanged). Thread = (channel d, m).
// All 32 chunk partials prefetched upfront (1-KB wave runs), then serial
// shfl chain. s_j = Apow*s_{j-1} + c_j ; hin_j = s_{j-1}.
// ---------------------------------------------------------------------------
__global__ __launch_bounds__(256) void k2_carry(const float* __restrict__ cbuf,
                                                float* __restrict__ ws) {
    const int blk = blockIdx.x;           // 256 blocks
    const int b   = blk >> 6;
    const int d0  = (blk & 63) * 16;
    const int t   = threadIdx.x;
    const int m   = t & 15;
    const int ch  = t >> 4;
    const int d   = d0 + ch;
    const int laneBase = t & 48;          // 16-lane group base within wave

    const size_t base0   = (((size_t)(b * NCH) * DMODEL) + d) * 16 + m;
    const size_t jstride = (size_t)DMODEL * 16;

    float cpre[NCH];
    #pragma unroll
    for (int j = 0; j < NCH; ++j)
        cpre[j] = cbuf[base0 + (size_t)j * jstride];

    float Arow[16];
    #pragma unroll
    for (int k = 0; k < 16; ++k) Arow[k] = ws[WS_APOW + m * 16 + k];

    float* hin = ws + WS_HIN;
    float s = 0.0f;
    #pragma unroll
    for (int j = 0; j < NCH; ++j) {
        hin[base0 + (size_t)j * jstride] = s;
        float acc = cpre[j];
        #pragma unroll
        for (int k = 0; k < 16; ++k)
            acc = fmaf(Arow[k], __shfl(s, laneBase + k, 64), acc);
        s = acc;
    }
}

// ---------------------------------------------------------------------------
// K3: outputs. Block (b, j, quarter-D), 256 threads. Same one-shot 64-KB
// LDS stage of x as K1 (16-deep float4 MLP). tau processed in 4 register
// tiles of 16 (yv[16] -> VGPR stays ~70, unlike R5's yv[64]/220-VGPR bust).
// y[tau] = W[tau].h_in + sum_{s<=tau} k[tau-s] x[s]; kv zero-pad covers
// tau<s inside a tile's last 16 sigmas.
// ---------------------------------------------------------------------------
__global__ __launch_bounds__(256) void k3_output(const float* __restrict__ x,
                                                 const float* __restrict__ ws,
                                                 float* __restrict__ y) {
    __shared__ __align__(16) float xs[CT * 256];        // 64 KB
    __shared__ float kvs[128];                          // 512 B
    __shared__ float Ws[CT * 16];                       // 4 KB
    const int blk = blockIdx.x;           // 512 = ((b*32 + j)*4 + q)
    const int b   = blk >> 7;
    const int j   = (blk >> 2) & 31;
    const int q   = blk & 3;
    const int t   = threadIdx.x;          // 0..255
    const int d   = q * 256 + t;

    const float* __restrict__ xq =
        x + ((size_t)(b * SEQL + j * CT)) * DMODEL + q * 256;

    // stage x (16 independent float4 loads, 1-KB wave runs)
    float4 st[16];
    #pragma unroll
    for (int k = 0; k < 16; ++k) {
        const int f   = k * 256 + t;
        const int row = f >> 6;
        const int c4  = f & 63;
        st[k] = ((const float4*)(xq + (size_t)row * DMODEL))[c4];
    }
    // tables + h_in (contiguous float4 runs)
    if (t < 128) kvs[t] = ws[WS_KV + t];
    #pragma unroll
    for (int k = 0; k < 4; ++k) Ws[t + k * 256] = ws[WS_W + t + k * 256];
    const float4* hinp = (const float4*)(ws + WS_HIN +
                         (((size_t)(b * NCH + j) * DMODEL) + d) * 16);
    float4 hv[4];
    #pragma unroll
    for (int k = 0; k < 4; ++k) hv[k] = hinp[k];

    #pragma unroll
    for (int k = 0; k < 16; ++k) ((float4*)xs)[k * 256 + t] = st[k];
    __syncthreads();

    float h[16];
    #pragma unroll
    for (int k = 0; k < 4; ++k) {
        h[4 * k] = hv[k].x; h[4 * k + 1] = hv[k].y;
        h[4 * k + 2] = hv[k].z; h[4 * k + 3] = hv[k].w;
    }

    float* yp = y + ((size_t)(b * SEQL + j * CT)) * DMODEL + d;

    #pragma unroll
    for (int tt = 0; tt < 4; ++tt) {      // tau tiles of 16
        float yv[16];
        #pragma unroll
        for (int i = 0; i < 16; ++i) {    // correction: W[tau].h_in
            float acc = 0.0f;
            #pragma unroll
            for (int m = 0; m < 16; ++m)
                acc = fmaf(Ws[(tt * 16 + i) * 16 + m], h[m], acc);
            yv[i] = acc;
        }
        #pragma unroll
        for (int s = 0; s < tt * 16 + 16; ++s) {       // compile-time bound
            const float xv = xs[s * 256 + t];
            #pragma unroll
            for (int i = 0; i < 16; ++i)               // tau<s hits zero-pad
                yv[i] = fmaf(kvs[63 + tt * 16 + i - s], xv, yv[i]);
        }
        #pragma unroll
        for (int i = 0; i < 16; ++i)
            yp[(size_t)(tt * 16 + i) * DMODEL] = yv[i];
    }
}

// ---------------------------------------------------------------------------
extern "C" void kernel_launch(void* const* d_in, const int* in_sizes, int n_in,
                              void* d_out, int out_size, void* d_ws, size_t ws_size,
                              hipStream_t stream) {
    (void)in_sizes; (void)n_in; (void)out_size; (void)ws_size;
    const float* x  = (const float*)d_in[0];
    const float* A  = (const float*)d_in[1];
    const float* Bv = (const float*)d_in[2];
    float* out = (float*)d_out;
    float* ws  = (float*)d_ws;

    // c scratch lives in d_out (dead before K3 overwrites it with y);
    // h_in + tables in ws.
    setup_tables<<<65, 256, 0, stream>>>(A, Bv, ws);
    k1_chunkstate<<<512, 256, 0, stream>>>(x, ws, out);
    k2_carry<<<256, 256, 0, stream>>>(out, ws);
    k3_output<<<512, 256, 0, stream>>>(x, ws, out);
}